// Round 1
// baseline (16.711 us; speedup 1.0000x reference)
//
#include <hip/hip_runtime.h>
#include <hip/hip_bf16.h>

#define VOCAB 50257
#define DIM 512
#define PAD_IDX 0

// out[t, :] = raw_weight[x[t], :] * mask[x[t]]   (zero when x[t]==PAD_IDX)
// One float4 (16 B) per thread. 128 float4 per row -> a wave's 64 lanes all
// share one row => wave-uniform index/mask loads, fully coalesced gather.
__global__ __launch_bounds__(256) void vdemb_kernel(
    const int* __restrict__ x,
    const float* __restrict__ w,
    const float* __restrict__ mask,
    float* __restrict__ out,
    int n_float4)   // total float4s = tokens * DIM/4
{
    int g = blockIdx.x * blockDim.x + threadIdx.x;
    if (g >= n_float4) return;

    const int f4_per_row = DIM / 4;            // 128
    int row = g >> 7;                          // g / 128
    int d4  = g & (f4_per_row - 1);            // g % 128

    int idx = x[row];                          // wave-uniform
    float scale = (idx != PAD_IDX) ? mask[idx] : 0.0f;

    const float4* wrow = reinterpret_cast<const float4*>(w + (size_t)idx * DIM);
    float4 v = wrow[d4];
    v.x *= scale; v.y *= scale; v.z *= scale; v.w *= scale;

    reinterpret_cast<float4*>(out)[g] = v;
}

extern "C" void kernel_launch(void* const* d_in, const int* in_sizes, int n_in,
                              void* d_out, int out_size, void* d_ws, size_t ws_size,
                              hipStream_t stream) {
    const int*   x    = (const int*)d_in[0];     // 8*2048 token ids
    const float* w    = (const float*)d_in[1];   // 50257*512 fp32
    const float* mask = (const float*)d_in[2];   // 50257 fp32
    float* out = (float*)d_out;

    int tokens = in_sizes[0];                    // 16384
    int n_float4 = tokens * (DIM / 4);           // 2,097,152

    int block = 256;
    int grid = (n_float4 + block - 1) / block;   // 8192
    vdemb_kernel<<<grid, block, 0, stream>>>(x, w, mask, out, n_float4);
}

// Round 3
// 15.817 us; speedup vs baseline: 1.0565x; 1.0565x over previous
//
#include <hip/hip_runtime.h>
#include <hip/hip_bf16.h>

#define VOCAB 50257
#define DIM 512
#define PAD_IDX 0
#define F4_PER_ROW (DIM / 4)   // 128

// Native clang vector type: accepted by __builtin_nontemporal_store,
// same 16B layout/alignment as float4.
typedef float f32x4 __attribute__((ext_vector_type(4)));

// out[t, :] = raw_weight[x[t], :] * mask[x[t]]   (zero when x[t]==PAD_IDX)
//
// Grid-stride hard-unrolled x4: each thread owns exactly 4 float4s spaced
// gridDim*blockDim apart. The 4 iterations are fully independent -> 4
// outstanding load/store chains per lane. Stores are nontemporal: out is
// write-once, keep L2 for the repeated-token weight-row gather.
__global__ __launch_bounds__(256) void vdemb_kernel(
    const int* __restrict__ x,
    const float* __restrict__ w,
    const float* __restrict__ mask,
    float* __restrict__ out,
    int n_float4)
{
    const int stride = gridDim.x * blockDim.x;
    const int g0 = blockIdx.x * blockDim.x + threadIdx.x;
    const f32x4* __restrict__ w4 = reinterpret_cast<const f32x4*>(w);
    f32x4* __restrict__ o4 = reinterpret_cast<f32x4*>(out);

    int g1 = g0 + stride, g2 = g1 + stride, g3 = g2 + stride;

    if (g3 < n_float4) {
        // fast path: all 4 in range (exact fit for the shipped shape)
        int r0 = g0 >> 7, r1 = g1 >> 7, r2 = g2 >> 7, r3 = g3 >> 7;
        int i0 = x[r0], i1 = x[r1], i2 = x[r2], i3 = x[r3];
        float s0 = (i0 != PAD_IDX) ? mask[i0] : 0.0f;
        float s1 = (i1 != PAD_IDX) ? mask[i1] : 0.0f;
        float s2 = (i2 != PAD_IDX) ? mask[i2] : 0.0f;
        float s3 = (i3 != PAD_IDX) ? mask[i3] : 0.0f;
        f32x4 v0 = w4[(size_t)i0 * F4_PER_ROW + (g0 & 127)];
        f32x4 v1 = w4[(size_t)i1 * F4_PER_ROW + (g1 & 127)];
        f32x4 v2 = w4[(size_t)i2 * F4_PER_ROW + (g2 & 127)];
        f32x4 v3 = w4[(size_t)i3 * F4_PER_ROW + (g3 & 127)];
        v0 *= s0; v1 *= s1; v2 *= s2; v3 *= s3;
        __builtin_nontemporal_store(v0, &o4[g0]);
        __builtin_nontemporal_store(v1, &o4[g1]);
        __builtin_nontemporal_store(v2, &o4[g2]);
        __builtin_nontemporal_store(v3, &o4[g3]);
    } else {
        // tail path (only used for shapes that don't divide evenly)
        for (int g = g0; g < n_float4; g += stride) {
            int row = g >> 7;
            int idx = x[row];
            float s = (idx != PAD_IDX) ? mask[idx] : 0.0f;
            f32x4 v = w4[(size_t)idx * F4_PER_ROW + (g & 127)];
            v *= s;
            __builtin_nontemporal_store(v, &o4[g]);
        }
    }
}

extern "C" void kernel_launch(void* const* d_in, const int* in_sizes, int n_in,
                              void* d_out, int out_size, void* d_ws, size_t ws_size,
                              hipStream_t stream) {
    const int*   x    = (const int*)d_in[0];     // 8*2048 token ids (int32)
    const float* w    = (const float*)d_in[1];   // 50257*512 fp32
    const float* mask = (const float*)d_in[2];   // 50257 fp32
    float* out = (float*)d_out;

    int tokens = in_sizes[0];                    // 16384
    int n_float4 = tokens * F4_PER_ROW;          // 2,097,152

    const int block = 256;
    const int unroll = 4;
    int grid = (n_float4 + block * unroll - 1) / (block * unroll);  // 2048
    vdemb_kernel<<<grid, block, 0, stream>>>(x, w, mask, out, n_float4);
}